// Round 9
// baseline (299.085 us; speedup 1.0000x reference)
//
#include <hip/hip_runtime.h>
#include <hip/hip_bf16.h>
#include <stdint.h>

// Problem constants: B=4, N=2048, D=1024, H=16, hd=64, NCTX=512
#define BATCH  4
#define NSEQ   2048
#define DMODEL 1024
#define NHEAD  16
#define HDIM   64
#define NCTXC  512

typedef unsigned short u16;
typedef __attribute__((ext_vector_type(8))) short bfrag;   // 8 bf16 = 4 VGPRs (MFMA A/B operand)
typedef __attribute__((ext_vector_type(4))) float facc;    // MFMA C/D operand

typedef __attribute__((address_space(3))) void lds_void;
typedef __attribute__((address_space(1))) void g_void;

__device__ __forceinline__ void gload16(const void* g, void* l) {
  __builtin_amdgcn_global_load_lds((const g_void*)g, (lds_void*)l, 16, 0, 0);
}

// bf16 conversion via HW v_cvt_pk_bf16_f32 (gfx950 has the instruction but no
// builtin — learn_hip m240). RNE rounding.
__device__ __forceinline__ u16 f2bf(float f) {
  uint32_t r;
  asm("v_cvt_pk_bf16_f32 %0, %1, %1" : "=v"(r) : "v"(f));
  return (u16)r;
}

#if __has_builtin(__builtin_amdgcn_cvt_pk_bf16_f32)
__device__ __forceinline__ uint32_t pk2bf(float a, float b) {
  return __builtin_bit_cast(uint32_t, __builtin_amdgcn_cvt_pk_bf16_f32(a, b));
}
#else
__device__ __forceinline__ uint32_t pk2bf(float a, float b) {
  uint32_t r;
  asm("v_cvt_pk_bf16_f32 %0, %1, %2" : "=v"(r) : "v"(a), "v"(b));
  return r;
}
#endif

__device__ __forceinline__ float bf2f(u16 h) {
  union { uint32_t u; float f; } un;
  un.u = ((uint32_t)h) << 16;
  return un.f;
}

__device__ __forceinline__ float load_flex(const void* p, size_t idx, int isb) {
  return isb ? bf2f(((const u16*)p)[idx]) : ((const float*)p)[idx];
}

__device__ __forceinline__ uint4 pack8(float4 a, float4 b) {
  uint4 r;
  r.x = pk2bf(a.x, a.y);
  r.y = pk2bf(a.z, a.w);
  r.z = pk2bf(b.x, b.y);
  r.w = pk2bf(b.z, b.w);
  return r;
}

// per-block inline dtype detection — EXACT replica of the old detect_kernel
// (same 4096 sampled elements, same thresholds). 8 KB of L2-hot reads + one
// shared reduction; sub-µs per block. Removes the detect launch + flag dep.
__device__ __forceinline__ int detect_isb_block(const u16* __restrict__ xraw) {
  __shared__ int s_high, s_zero;
  const int tid = threadIdx.x;      // 256-thread blocks only
  if (tid == 0) { s_high = 0; s_zero = 0; }
  __syncthreads();
  int h = 0, z = 0;
  for (int i = tid; i < 4096; i += 256) {
    const u16 v = xraw[2 * i];
    const int e = (v >> 7) & 0xFF;
    if (e >= 0x90) h++;
    if (v == 0) z++;
  }
  atomicAdd(&s_high, h);
  atomicAdd(&s_zero, z);
  __syncthreads();
  return (s_high < 64 && s_zero < 2048) ? 1 : 0;
}

// ---------------------------------------------------------------- fused prep
// R9: ONE kernel replaces {detect, cast_x, transpose W_in, transpose W_out,
// prep_small} — 5 launches → 1. Role decoded from blockIdx; every block
// self-detects isb; block 0 persists flag[0] for gemm_out (which launches
// after two intervening kernels — stream order guarantees visibility).
__global__ __launch_bounds__(256) void prep_all(const void* __restrict__ x,
                                                u16* __restrict__ xb,
                                                const void* __restrict__ W_in,
                                                const void* __restrict__ W_out,
                                                u16* __restrict__ Wt,
                                                u16* __restrict__ WoT,
                                                const void* __restrict__ b_in,
                                                const void* __restrict__ b_out,
                                                const void* __restrict__ ppr,
                                                const void* __restrict__ trust,
                                                const void* __restrict__ alpha_p,
                                                const void* __restrict__ ts_p,
                                                float* __restrict__ bin_f,
                                                float* __restrict__ bout_f,
                                                float* __restrict__ gate,
                                                float* __restrict__ cbias,
                                                int* __restrict__ flag) {
  __shared__ float tile[32][33];
  const int isb = detect_isb_block((const u16*)x);
  const int bid = blockIdx.x;
  const int tid = threadIdx.x;
  if (bid == 0 && tid == 0) flag[0] = isb;

  if (bid < 4096) {
    // ---- cast_x role (4096 blocks)
    const int i = bid * 256 + tid;
    if (isb) {
      ((uint4*)xb)[i] = ((const uint4*)x)[i];
    } else {
      const float4 f0 = ((const float4*)x)[2 * i];
      const float4 f1 = ((const float4*)x)[2 * i + 1];
      ((uint4*)xb)[i] = pack8(f0, f1);
    }
  } else if (bid < 4096 + 3072 + 1024) {
    // ---- transpose roles: W_in (3072 blocks, C=3072) then W_out (1024, C=1024)
    const int win = (bid < 4096 + 3072);
    const int b2  = win ? (bid - 4096) : (bid - 4096 - 3072);
    const int nbx = win ? 96 : 32;
    const int C   = win ? 3072 : 1024;
    const void* W = win ? W_in : W_out;
    u16* WtD      = win ? Wt : WoT;
    const int R   = 1024;
    const int c0  = (b2 % nbx) * 32;
    const int r0  = (b2 / nbx) * 32;
    const int tx  = tid & 31;
    const int ty  = tid >> 5;       // 0..7
#pragma unroll
    for (int j = 0; j < 32; j += 8)
      tile[ty + j][tx] = load_flex(W, (size_t)(r0 + ty + j) * C + c0 + tx, isb);
    __syncthreads();
#pragma unroll
    for (int j = 0; j < 32; j += 8)
      WtD[(size_t)(c0 + ty + j) * R + r0 + tx] = f2bf(tile[tx][ty + j]);
  } else {
    // ---- prep_small role (24 blocks)
    const int i = (bid - 4096 - 3072 - 1024) * 256 + tid;
    if (i < 3072) {
      bin_f[i] = load_flex(b_in, i, isb);
    } else if (i < 4096) {
      bout_f[i - 3072] = load_flex(b_out, i - 3072, isb);
    } else if (i < 4096 + BATCH * NCTXC) {
      const int j = i - 4096;
      const float ts = load_flex(ts_p, 0, isb), al = load_flex(alpha_p, 0, isb);
      gate[j]  = 1.0f / (1.0f + __expf(-ts * load_flex(trust, j, isb)));
      cbias[j] = -al * logf(fmaxf(load_flex(ppr, j, isb), 1e-8f)) * 1.44269504f;
    }
  }
}

// ---------------------------------------------------------------- shared K-loop (m97 staging)
__device__ __forceinline__ void kloop_mfma(const u16* __restrict__ Ag,
                                           const u16* __restrict__ Bg,
                                           u16* As, u16* Bs,
                                           int tid, int wM, int wN, int l16, int quad,
                                           facc acc[4][4]) {
  char* ldsA = (char*)As + tid * 16;
  char* ldsB = (char*)Bs + tid * 16;
  for (int k0 = 0; k0 < 1024; k0 += 32) {
    __syncthreads();
    gload16(Ag + k0, ldsA);
    gload16(Ag + (size_t)64 * 1024 + k0, ldsA + 4096);
    gload16(Bg + k0, ldsB);
    gload16(Bg + (size_t)64 * 1024 + k0, ldsB + 4096);
    __syncthreads();

    bfrag af[4], bf[4];
#pragma unroll
    for (int i = 0; i < 4; ++i)
      af[i] = *(const bfrag*)(&As[(wM + i * 16 + l16) * 32 + quad * 8]);
#pragma unroll
    for (int j = 0; j < 4; ++j)
      bf[j] = *(const bfrag*)(&Bs[(wN + j * 16 + l16) * 32 + quad * 8]);
#pragma unroll
    for (int i = 0; i < 4; ++i)
#pragma unroll
      for (int j = 0; j < 4; ++j)
        acc[i][j] = __builtin_amdgcn_mfma_f32_16x16x32_bf16(af[i], bf[j], acc[i][j], 0, 0, 0);
  }
}

// ---------------------------------------------------------------- merged QK + V^T GEMM
// T1 XCD-bijective block swizzle (1536 = 8 x 192); V^T half bn-major.
__global__ __launch_bounds__(256) void gemm_qkvt(const u16* __restrict__ xb,
                                                 const u16* __restrict__ Wt,
                                                 const float* __restrict__ bin_f,
                                                 const float* __restrict__ gate,
                                                 u16* __restrict__ qk,
                                                 u16* __restrict__ Vtg) {
  __shared__ u16 As[128 * 32];
  __shared__ u16 Bs[128 * 32];
  const int tid  = threadIdx.x;
  const int w    = tid >> 6;
  const int lane = tid & 63;
  const int quad = lane >> 4;
  const int l16  = lane & 15;
  const int wM   = (w >> 1) * 64;
  const int wN   = (w & 1) * 64;
  const int bid  = blockIdx.x;
  const int id   = (bid & 7) * 192 + (bid >> 3);   // XCD-bijective remap
  const int srow  = tid >> 2;
  const int spart = tid & 3;

  facc acc[4][4] = {};

  if (id < 1024) {
    const int bn = id & 15, bm = id >> 4;
    const u16* Ag = xb + (size_t)(bm * 128 + srow) * 1024 + spart * 8;
    const u16* Bg = Wt + (size_t)(bn * 128 + srow) * 1024 + spart * 8;
    kloop_mfma(Ag, Bg, As, Bs, tid, wM, wN, l16, quad, acc);

    const float qs = (bn < 8) ? 0.18033688f : 1.0f;
#pragma unroll
    for (int i = 0; i < 4; ++i) {
      const int grow0 = bm * 128 + wM + i * 16 + quad * 4;
#pragma unroll
      for (int j = 0; j < 4; ++j) {
        const int gcol = bn * 128 + wN + j * 16 + l16;
        const float bv = bin_f[gcol];
#pragma unroll
        for (int r = 0; r < 4; ++r)
          qk[(size_t)(grow0 + r) * 2048 + gcol] = f2bf((acc[i][j][r] + bv) * qs);
      }
    }
  } else {
    const int id2 = id - 1024;
    const int bn = id2 >> 3, bm = id2 & 7;          // bn-major (Wv stays L2-hot)
    const u16* Ag = Wt + (size_t)2048 * 1024 + (size_t)(bm * 128 + srow) * 1024 + spart * 8;
    const u16* Bg = xb + (size_t)(bn * 128 + srow) * 1024 + spart * 8;
    kloop_mfma(Ag, Bg, As, Bs, tid, wM, wN, l16, quad, acc);

#pragma unroll
    for (int i = 0; i < 4; ++i) {
      const int grow0 = bm * 128 + wM + i * 16 + quad * 4;
      const int h   = grow0 >> 6;
      const int dd0 = grow0 & 63;
#pragma unroll
      for (int j = 0; j < 4; ++j) {
        const int gcol = bn * 128 + wN + j * 16 + l16;
        const int bb  = gcol >> 11;
        const int tok = gcol & (NSEQ - 1);
        const float gl = (tok < NCTXC) ? gate[bb * NCTXC + tok] : 1.0f;
        u16* dst = &Vtg[((size_t)((bb * NHEAD + h) * HDIM + dd0)) * NSEQ + tok];
#pragma unroll
        for (int r = 0; r < 4; ++r)
          dst[(size_t)r * NSEQ] = f2bf((acc[i][j][r] + bin_f[2 * DMODEL + grow0 + r]) * gl);
      }
    }
  }
}

// ---------------------------------------------------------------- output GEMM (m97 staging)
// 1-D grid (512 = 8 x 64) with T1 swizzle.
__global__ __launch_bounds__(256) void gemm_out(const u16* __restrict__ A,
                                                const u16* __restrict__ Bt,
                                                const float* __restrict__ biasf,
                                                void* __restrict__ Cout,
                                                const int* __restrict__ flag) {
  __shared__ u16 As[128 * 32];
  __shared__ u16 Bs[128 * 32];
  const int isb  = flag[0];
  const int tid  = threadIdx.x;
  const int w    = tid >> 6;
  const int lane = tid & 63;
  const int quad = lane >> 4;
  const int l16  = lane & 15;
  const int wM   = (w >> 1) * 64;
  const int wN   = (w & 1) * 64;
  const int bid  = blockIdx.x;
  const int id   = (bid & 7) * 64 + (bid >> 3);    // XCD-bijective remap
  const int bn   = id & 7;
  const int bm   = id >> 3;
  const int srow  = tid >> 2;
  const int spart = tid & 3;

  facc acc[4][4] = {};
  const u16* Ag = A + (size_t)(bm * 128 + srow) * 2048 + spart * 8;
  const u16* Bg = Bt + (size_t)(bn * 128 + srow) * 1024 + spart * 8;
  char* ldsA = (char*)As + tid * 16;
  char* ldsB = (char*)Bs + tid * 16;

  for (int k0 = 0; k0 < 1024; k0 += 32) {
    __syncthreads();
    gload16(Ag + k0, ldsA);
    gload16(Ag + (size_t)64 * 2048 + k0, ldsA + 4096);
    gload16(Bg + k0, ldsB);
    gload16(Bg + (size_t)64 * 1024 + k0, ldsB + 4096);
    __syncthreads();

    bfrag af[4], bf[4];
#pragma unroll
    for (int i = 0; i < 4; ++i)
      af[i] = *(const bfrag*)(&As[(wM + i * 16 + l16) * 32 + quad * 8]);
#pragma unroll
    for (int j = 0; j < 4; ++j)
      bf[j] = *(const bfrag*)(&Bs[(wN + j * 16 + l16) * 32 + quad * 8]);
#pragma unroll
    for (int i = 0; i < 4; ++i)
#pragma unroll
      for (int j = 0; j < 4; ++j)
        acc[i][j] = __builtin_amdgcn_mfma_f32_16x16x32_bf16(af[i], bf[j], acc[i][j], 0, 0, 0);
  }

#pragma unroll
  for (int i = 0; i < 4; ++i) {
    const int grow0 = bm * 128 + wM + i * 16 + quad * 4;
#pragma unroll
    for (int j = 0; j < 4; ++j) {
      const int gcol = bn * 128 + wN + j * 16 + l16;
      const float bv = biasf[gcol];
#pragma unroll
      for (int r = 0; r < 4; ++r) {
        const float v = acc[i][j][r] + bv;
        if (isb) ((u16*)Cout)[(size_t)(grow0 + r) * 1024 + gcol] = f2bf(v);
        else     ((float*)Cout)[(size_t)(grow0 + r) * 1024 + gcol] = v;
      }
    }
  }
}

// ---------------------------------------------------------------- flash attention
// R5/R8 structure (proven): 2 waves × 64 q each, gload_lds dbuf K/V with
// both-sides XOR swizzle, in-register P via MFMA k-order freedom, MFMA den.
__global__ __launch_bounds__(128, 2) void attn_kernel(u16* __restrict__ qk,
                                                      const u16* __restrict__ vtg,
                                                      const float* __restrict__ cbias) {
  const int id    = blockIdx.x;             // 0..1023
  const int chunk = id >> 3;
  const int qt    = chunk & 15;
  const int hg    = (id & 7) | ((chunk >> 4) << 3);
  const int h     = hg & 15;
  const int b     = hg >> 4;

  __shared__ u16 KV[2][2][64 * 64];  // [buf][K|V][row*64+col], linear, src-swizzled

  const int tid  = threadIdx.x;      // 0..127
  const int w    = tid >> 6;         // 0..1
  const int lane = tid & 63;
  const int quad = lane >> 4;
  const int l16  = lane & 15;

  // Q: wave w owns q rows qt*128 + w*64 + qs*16 + l16, qs = 0..3
  bfrag bq[4][2];
#pragma unroll
  for (int qs = 0; qs < 4; ++qs) {
    const u16* qrow = qk + (size_t)(b * NSEQ + qt * 128 + w * 64 + qs * 16 + l16) * 2048 + h * HDIM;
    bq[qs][0] = *(const bfrag*)(qrow + quad * 8);
    bq[qs][1] = *(const bfrag*)(qrow + 32 + quad * 8);
  }

  // ones A-fragment for the denominator MFMA (k-order invariant)
  bfrag ones;
#pragma unroll
  for (int i = 0; i < 8; ++i) ones[i] = (short)0x3F80;   // bf16 1.0

  facc den[4] = {};
  facc o[4][4] = {};

  const u16* kbase = qk + (size_t)(b * NSEQ) * 2048 + DMODEL + h * HDIM;
  const u16* vbase = vtg + (size_t)((b * NHEAD + h) * HDIM) * NSEQ;

  // staging chunk map: chunk c = tid + i*128 → row c>>3, swizzled 16B-slot (c&7)^(row&7)
  int crow[4], csc[4];
#pragma unroll
  for (int i = 0; i < 4; ++i) {
    const int c = tid + i * 128;
    crow[i] = c >> 3;
    csc[i]  = (c & 7) ^ (crow[i] & 7);
  }

  // read-side swizzle constants (elem offsets)
  const int e    = l16 & 7;
  const int swk0 = (quad ^ e) * 8;                 // K half-0 chunk
  const int cA0  = ((quad >> 1) ^ e) * 8 + (quad & 1) * 4;  // V base

  auto stage = [&](int sel, int t) {
#pragma unroll
    for (int i = 0; i < 4; ++i) {
      const int c = tid + i * 128;
      gload16(kbase + (size_t)(t * 64 + crow[i]) * 2048 + csc[i] * 8, &KV[sel][0][c * 8]);
      gload16(vbase + (size_t)crow[i] * 2048 + t * 64 + csc[i] * 8,   &KV[sel][1][c * 8]);
    }
  };

  stage(0, 0);

  for (int t = 0; t < NSEQ / 64; ++t) {
    __syncthreads();                 // drains own gloads (implicit vmcnt(0)) + barrier
    if (t + 1 < NSEQ / 64) stage((t + 1) & 1, t + 1);   // writes the OTHER buffer

    const u16* Kb = KV[t & 1][0];
    const u16* Vb = KV[t & 1][1];

    // K fragments (swizzled b128)
    bfrag ak[4][2];
#pragma unroll
    for (int nt = 0; nt < 4; ++nt) {
      const u16* kr = &Kb[(nt * 16 + l16) * 64];
      ak[nt][0] = *(const bfrag*)(kr + swk0);
      ak[nt][1] = *(const bfrag*)(kr + (swk0 ^ 32));
    }

    // V fragments in the bp-matching k-order (swizzled b64 pairs):
    // av[dt][half] elem j = V^T[dt*16+l16][ half*32 + (j>>2)*16 + quad*4 + (j&3) ]
    bfrag av[4][2];
#pragma unroll
    for (int dt = 0; dt < 4; ++dt) {
      const u16* vr = &Vb[(dt * 16 + l16) * 64];
      union { bfrag f; uint2 u2[2]; } un0, un1;
      un0.u2[0] = *(const uint2*)(vr + cA0);
      un0.u2[1] = *(const uint2*)(vr + (cA0 ^ 16));
      un1.u2[0] = *(const uint2*)(vr + (cA0 ^ 32));
      un1.u2[1] = *(const uint2*)(vr + (cA0 ^ 48));
      av[dt][0] = un0.f;
      av[dt][1] = un1.f;
    }

    // per-tile column bias as MFMA C-init (kv-only, shared by all qs)
    facc zb[4];
    if (t < 8) {
      const float* cb = cbias + b * NCTXC + t * 64 + quad * 4;
#pragma unroll
      for (int nt = 0; nt < 4; ++nt) zb[nt] = *(const facc*)(cb + nt * 16);
    } else {
#pragma unroll
      for (int nt = 0; nt < 4; ++nt) zb[nt] = (facc){};
    }

    // 4 q-subtiles: QK -> exp2 -> in-register pack -> PV + den
#pragma unroll
    for (int qs = 0; qs < 4; ++qs) {
      facc s[4];
      __builtin_amdgcn_s_setprio(1);
#pragma unroll
      for (int nt = 0; nt < 4; ++nt) {
        facc z = zb[nt];
        z = __builtin_amdgcn_mfma_f32_16x16x32_bf16(ak[nt][0], bq[qs][0], z, 0, 0, 0);
        s[nt] = __builtin_amdgcn_mfma_f32_16x16x32_bf16(ak[nt][1], bq[qs][1], z, 0, 0, 0);
      }
      __builtin_amdgcn_s_setprio(0);

#pragma unroll
      for (int nt = 0; nt < 4; ++nt)
#pragma unroll
        for (int r = 0; r < 4; ++r)
          s[nt][r] = __builtin_amdgcn_exp2f(s[nt][r]);

      // bp[half] slot j holds P[kv = half*32 + (j>>2)*16 + quad*4 + (j&3)][l16]
      union { bfrag f; uint32_t wrd[4]; } bp0, bp1;
      bp0.wrd[0] = pk2bf(s[0][0], s[0][1]);
      bp0.wrd[1] = pk2bf(s[0][2], s[0][3]);
      bp0.wrd[2] = pk2bf(s[1][0], s[1][1]);
      bp0.wrd[3] = pk2bf(s[1][2], s[1][3]);
      bp1.wrd[0] = pk2bf(s[2][0], s[2][1]);
      bp1.wrd[1] = pk2bf(s[2][2], s[2][3]);
      bp1.wrd[2] = pk2bf(s[3][0], s[3][1]);
      bp1.wrd[3] = pk2bf(s[3][2], s[3][3]);

      __builtin_amdgcn_s_setprio(1);
#pragma unroll
      for (int dt = 0; dt < 4; ++dt) {
        o[qs][dt] = __builtin_amdgcn_mfma_f32_16x16x32_bf16(av[dt][0], bp0.f, o[qs][dt], 0, 0, 0);
        o[qs][dt] = __builtin_amdgcn_mfma_f32_16x16x32_bf16(av[dt][1], bp1.f, o[qs][dt], 0, 0, 0);
      }
      den[qs] = __builtin_amdgcn_mfma_f32_16x16x32_bf16(ones, bp0.f, den[qs], 0, 0, 0);
      den[qs] = __builtin_amdgcn_mfma_f32_16x16x32_bf16(ones, bp1.f, den[qs], 0, 0, 0);
      __builtin_amdgcn_s_setprio(0);
    }
  }

  // epilogue: every lane holds its q-column's denominator at den[qs][0]
#pragma unroll
  for (int qs = 0; qs < 4; ++qs) {
    const float inv = 1.0f / den[qs][0];
    u16* orow = qk + (size_t)(b * NSEQ + qt * 128 + w * 64 + qs * 16 + l16) * 2048 + h * HDIM;
#pragma unroll
    for (int dt = 0; dt < 4; ++dt) {
      uint2 st;
      st.x = pk2bf(o[qs][dt][0] * inv, o[qs][dt][1] * inv);
      st.y = pk2bf(o[qs][dt][2] * inv, o[qs][dt][3] * inv);
      *(uint2*)(orow + dt * 16 + quad * 4) = st;
    }
  }
}

// ---------------------------------------------------------------- launch

extern "C" void kernel_launch(void* const* d_in, const int* in_sizes, int n_in,
                              void* d_out, int out_size, void* d_ws, size_t ws_size,
                              hipStream_t stream) {
  const void* x          = d_in[0];
  const void* ctx_ppr    = d_in[1];
  const void* ctx_trust  = d_in[2];
  const void* W_in       = d_in[3];
  const void* b_in       = d_in[4];
  const void* W_out      = d_in[5];
  const void* b_out      = d_in[6];
  const void* lppr_alpha = d_in[7];
  const void* tscale     = d_in[8];

  char* ws = (char*)d_ws;
  u16* Wt    = (u16*)ws;  ws += (size_t)3072 * 1024 * 2;    //  6 MB  W_in^T bf16
  u16* WoT   = (u16*)ws;  ws += (size_t)1024 * 1024 * 2;    //  2 MB  W_out^T bf16
  u16* qk    = (u16*)ws;  ws += (size_t)8192 * 2048 * 2;    // 32 MB  [Q|K]; attn-out overwrites Q-plane
  u16* Vtg   = (u16*)ws;  ws += (size_t)64 * 64 * 2048 * 2; // 16 MB  gated V^T [b*16+h][d][n]
  u16* xb    = (u16*)ws;  ws += (size_t)8192 * 1024 * 2;    // 16 MB  x as bf16
  float* bin_f  = (float*)ws; ws += 3072 * 4;
  float* bout_f = (float*)ws; ws += 1024 * 4;
  float* gate   = (float*)ws; ws += (size_t)BATCH * NCTXC * 4;
  float* cbias  = (float*)ws; ws += (size_t)BATCH * NCTXC * 4;
  int*   flag   = (int*)ws;   ws += 64;

  // fused prep: detect (inline per block) + cast_x + both transposes + small
  // preps — 5 launches folded into 1. Block 0 persists flag for gemm_out.
  prep_all<<<dim3(4096 + 3072 + 1024 + 24), dim3(256), 0, stream>>>(
      x, xb, W_in, W_out, Wt, WoT, b_in, b_out, ctx_ppr, ctx_trust,
      lppr_alpha, tscale, bin_f, bout_f, gate, cbias, flag);
  // merged QK GEMM (1024 blocks) + V^T GEMM (512 blocks), XCD-swizzled
  gemm_qkvt<<<dim3(1536), dim3(256), 0, stream>>>(xb, Wt, bin_f, gate, qk, Vtg);
  // fused biased attention (128-q, XCD-swizzled, 2 waves × 64 q, gload_lds dbuf)
  attn_kernel<<<dim3(1024), dim3(128), 0, stream>>>(qk, Vtg, cbias);
  // output GEMM: [8192x1024 (lda 2048)] @ [1024x1024] (+b_out) -> d_out, XCD-swizzled
  gemm_out<<<dim3(512), dim3(256), 0, stream>>>(qk, WoT, bout_f, d_out, flag);
}

// Round 10
// 278.410 us; speedup vs baseline: 1.0743x; 1.0743x over previous
//
#include <hip/hip_runtime.h>
#include <hip/hip_bf16.h>
#include <stdint.h>

// Problem constants: B=4, N=2048, D=1024, H=16, hd=64, NCTX=512
#define BATCH  4
#define NSEQ   2048
#define DMODEL 1024
#define NHEAD  16
#define HDIM   64
#define NCTXC  512

typedef unsigned short u16;
typedef __attribute__((ext_vector_type(8))) short bfrag;   // 8 bf16 = 4 VGPRs (MFMA A/B operand)
typedef __attribute__((ext_vector_type(4))) float facc;    // MFMA C/D operand

typedef __attribute__((address_space(3))) void lds_void;
typedef __attribute__((address_space(1))) void g_void;

__device__ __forceinline__ void gload16(const void* g, void* l) {
  __builtin_amdgcn_global_load_lds((const g_void*)g, (lds_void*)l, 16, 0, 0);
}

// bf16 conversion via HW v_cvt_pk_bf16_f32 (gfx950 has the instruction but no
// builtin — learn_hip m240). RNE rounding.
__device__ __forceinline__ u16 f2bf(float f) {
  uint32_t r;
  asm("v_cvt_pk_bf16_f32 %0, %1, %1" : "=v"(r) : "v"(f));
  return (u16)r;
}

#if __has_builtin(__builtin_amdgcn_cvt_pk_bf16_f32)
__device__ __forceinline__ uint32_t pk2bf(float a, float b) {
  return __builtin_bit_cast(uint32_t, __builtin_amdgcn_cvt_pk_bf16_f32(a, b));
}
#else
__device__ __forceinline__ uint32_t pk2bf(float a, float b) {
  uint32_t r;
  asm("v_cvt_pk_bf16_f32 %0, %1, %2" : "=v"(r) : "v"(a), "v"(b));
  return r;
}
#endif

__device__ __forceinline__ float bf2f(u16 h) {
  union { uint32_t u; float f; } un;
  un.u = ((uint32_t)h) << 16;
  return un.f;
}

__device__ __forceinline__ float load_flex(const void* p, size_t idx, int isb) {
  return isb ? bf2f(((const u16*)p)[idx]) : ((const float*)p)[idx];
}

__device__ __forceinline__ uint4 pack8(float4 a, float4 b) {
  uint4 r;
  r.x = pk2bf(a.x, a.y);
  r.y = pk2bf(a.z, a.w);
  r.z = pk2bf(b.x, b.y);
  r.w = pk2bf(b.z, b.w);
  return r;
}

// ---------------------------------------------------------------- dtype detector
__global__ __launch_bounds__(256) void detect_kernel(const u16* __restrict__ xraw,
                                                     int* __restrict__ flag) {
  __shared__ int s_high, s_zero;
  if (threadIdx.x == 0) { s_high = 0; s_zero = 0; }
  __syncthreads();
  int h = 0, z = 0;
  for (int i = threadIdx.x; i < 4096; i += 256) {
    const u16 v = xraw[2 * i];
    const int e = (v >> 7) & 0xFF;
    if (e >= 0x90) h++;
    if (v == 0) z++;
  }
  atomicAdd(&s_high, h);
  atomicAdd(&s_zero, z);
  __syncthreads();
  if (threadIdx.x == 0) flag[0] = (s_high < 64 && s_zero < 2048) ? 1 : 0;
}

// ---------------------------------------------------------------- fused prep
// R10: fuse {cast_x, transpose W_in, transpose W_out, prep_small} into ONE
// kernel (role from blockIdx). Unlike R9, NO duplicated detect — blocks read
// flag[0] (the same pattern cast_x already used). Launches 8 -> 5.
__global__ __launch_bounds__(256) void prep_fused(const void* __restrict__ x,
                                                  u16* __restrict__ xb,
                                                  const void* __restrict__ W_in,
                                                  const void* __restrict__ W_out,
                                                  u16* __restrict__ Wt,
                                                  u16* __restrict__ WoT,
                                                  const void* __restrict__ b_in,
                                                  const void* __restrict__ b_out,
                                                  const void* __restrict__ ppr,
                                                  const void* __restrict__ trust,
                                                  const void* __restrict__ alpha_p,
                                                  const void* __restrict__ ts_p,
                                                  float* __restrict__ bin_f,
                                                  float* __restrict__ bout_f,
                                                  float* __restrict__ gate,
                                                  float* __restrict__ cbias,
                                                  const int* __restrict__ flag) {
  __shared__ float tile[32][33];
  const int isb = flag[0];
  const int bid = blockIdx.x;
  const int tid = threadIdx.x;

  if (bid < 4096) {
    // ---- cast_x role (4096 blocks) — byte-identical to R8's cast_x_kernel
    const int i = bid * 256 + tid;
    if (isb) {
      ((uint4*)xb)[i] = ((const uint4*)x)[i];
    } else {
      const float4 f0 = ((const float4*)x)[2 * i];
      const float4 f1 = ((const float4*)x)[2 * i + 1];
      ((uint4*)xb)[i] = pack8(f0, f1);
    }
  } else if (bid < 4096 + 3072 + 1024) {
    // ---- transpose roles: W_in (3072 blocks, C=3072) then W_out (1024, C=1024)
    const int win = (bid < 4096 + 3072);
    const int b2  = win ? (bid - 4096) : (bid - 4096 - 3072);
    const int nbx = win ? 96 : 32;
    const int C   = win ? 3072 : 1024;
    const void* W = win ? W_in : W_out;
    u16* WtD      = win ? Wt : WoT;
    const int R   = 1024;
    const int c0  = (b2 % nbx) * 32;
    const int r0  = (b2 / nbx) * 32;
    const int tx  = tid & 31;
    const int ty  = tid >> 5;       // 0..7
#pragma unroll
    for (int j = 0; j < 32; j += 8)
      tile[ty + j][tx] = load_flex(W, (size_t)(r0 + ty + j) * C + c0 + tx, isb);
    __syncthreads();
#pragma unroll
    for (int j = 0; j < 32; j += 8)
      WtD[(size_t)(c0 + ty + j) * R + r0 + tx] = f2bf(tile[tx][ty + j]);
  } else {
    // ---- prep_small role (24 blocks)
    const int i = (bid - 4096 - 3072 - 1024) * 256 + tid;
    if (i < 3072) {
      bin_f[i] = load_flex(b_in, i, isb);
    } else if (i < 4096) {
      bout_f[i - 3072] = load_flex(b_out, i - 3072, isb);
    } else if (i < 4096 + BATCH * NCTXC) {
      const int j = i - 4096;
      const float ts = load_flex(ts_p, 0, isb), al = load_flex(alpha_p, 0, isb);
      gate[j]  = 1.0f / (1.0f + __expf(-ts * load_flex(trust, j, isb)));
      cbias[j] = -al * logf(fmaxf(load_flex(ppr, j, isb), 1e-8f)) * 1.44269504f;
    }
  }
}

// ---------------------------------------------------------------- shared K-loop (m97 staging)
__device__ __forceinline__ void kloop_mfma(const u16* __restrict__ Ag,
                                           const u16* __restrict__ Bg,
                                           u16* As, u16* Bs,
                                           int tid, int wM, int wN, int l16, int quad,
                                           facc acc[4][4]) {
  char* ldsA = (char*)As + tid * 16;
  char* ldsB = (char*)Bs + tid * 16;
  for (int k0 = 0; k0 < 1024; k0 += 32) {
    __syncthreads();
    gload16(Ag + k0, ldsA);
    gload16(Ag + (size_t)64 * 1024 + k0, ldsA + 4096);
    gload16(Bg + k0, ldsB);
    gload16(Bg + (size_t)64 * 1024 + k0, ldsB + 4096);
    __syncthreads();

    bfrag af[4], bf[4];
#pragma unroll
    for (int i = 0; i < 4; ++i)
      af[i] = *(const bfrag*)(&As[(wM + i * 16 + l16) * 32 + quad * 8]);
#pragma unroll
    for (int j = 0; j < 4; ++j)
      bf[j] = *(const bfrag*)(&Bs[(wN + j * 16 + l16) * 32 + quad * 8]);
#pragma unroll
    for (int i = 0; i < 4; ++i)
#pragma unroll
      for (int j = 0; j < 4; ++j)
        acc[i][j] = __builtin_amdgcn_mfma_f32_16x16x32_bf16(af[i], bf[j], acc[i][j], 0, 0, 0);
  }
}

// ---------------------------------------------------------------- merged QK + V^T GEMM
// T1 XCD-bijective block swizzle (1536 = 8 x 192); V^T half bn-major.
__global__ __launch_bounds__(256) void gemm_qkvt(const u16* __restrict__ xb,
                                                 const u16* __restrict__ Wt,
                                                 const float* __restrict__ bin_f,
                                                 const float* __restrict__ gate,
                                                 u16* __restrict__ qk,
                                                 u16* __restrict__ Vtg) {
  __shared__ u16 As[128 * 32];
  __shared__ u16 Bs[128 * 32];
  const int tid  = threadIdx.x;
  const int w    = tid >> 6;
  const int lane = tid & 63;
  const int quad = lane >> 4;
  const int l16  = lane & 15;
  const int wM   = (w >> 1) * 64;
  const int wN   = (w & 1) * 64;
  const int bid  = blockIdx.x;
  const int id   = (bid & 7) * 192 + (bid >> 3);   // XCD-bijective remap
  const int srow  = tid >> 2;
  const int spart = tid & 3;

  facc acc[4][4] = {};

  if (id < 1024) {
    const int bn = id & 15, bm = id >> 4;
    const u16* Ag = xb + (size_t)(bm * 128 + srow) * 1024 + spart * 8;
    const u16* Bg = Wt + (size_t)(bn * 128 + srow) * 1024 + spart * 8;
    kloop_mfma(Ag, Bg, As, Bs, tid, wM, wN, l16, quad, acc);

    const float qs = (bn < 8) ? 0.18033688f : 1.0f;
#pragma unroll
    for (int i = 0; i < 4; ++i) {
      const int grow0 = bm * 128 + wM + i * 16 + quad * 4;
#pragma unroll
      for (int j = 0; j < 4; ++j) {
        const int gcol = bn * 128 + wN + j * 16 + l16;
        const float bv = bin_f[gcol];
#pragma unroll
        for (int r = 0; r < 4; ++r)
          qk[(size_t)(grow0 + r) * 2048 + gcol] = f2bf((acc[i][j][r] + bv) * qs);
      }
    }
  } else {
    const int id2 = id - 1024;
    const int bn = id2 >> 3, bm = id2 & 7;          // bn-major (Wv stays L2-hot)
    const u16* Ag = Wt + (size_t)2048 * 1024 + (size_t)(bm * 128 + srow) * 1024 + spart * 8;
    const u16* Bg = xb + (size_t)(bn * 128 + srow) * 1024 + spart * 8;
    kloop_mfma(Ag, Bg, As, Bs, tid, wM, wN, l16, quad, acc);

#pragma unroll
    for (int i = 0; i < 4; ++i) {
      const int grow0 = bm * 128 + wM + i * 16 + quad * 4;
      const int h   = grow0 >> 6;
      const int dd0 = grow0 & 63;
#pragma unroll
      for (int j = 0; j < 4; ++j) {
        const int gcol = bn * 128 + wN + j * 16 + l16;
        const int bb  = gcol >> 11;
        const int tok = gcol & (NSEQ - 1);
        const float gl = (tok < NCTXC) ? gate[bb * NCTXC + tok] : 1.0f;
        u16* dst = &Vtg[((size_t)((bb * NHEAD + h) * HDIM + dd0)) * NSEQ + tok];
#pragma unroll
        for (int r = 0; r < 4; ++r)
          dst[(size_t)r * NSEQ] = f2bf((acc[i][j][r] + bin_f[2 * DMODEL + grow0 + r]) * gl);
      }
    }
  }
}

// ---------------------------------------------------------------- output GEMM (m97 staging)
// 1-D grid (512 = 8 x 64) with T1 swizzle.
__global__ __launch_bounds__(256) void gemm_out(const u16* __restrict__ A,
                                                const u16* __restrict__ Bt,
                                                const float* __restrict__ biasf,
                                                void* __restrict__ Cout,
                                                const int* __restrict__ flag) {
  __shared__ u16 As[128 * 32];
  __shared__ u16 Bs[128 * 32];
  const int isb  = flag[0];
  const int tid  = threadIdx.x;
  const int w    = tid >> 6;
  const int lane = tid & 63;
  const int quad = lane >> 4;
  const int l16  = lane & 15;
  const int wM   = (w >> 1) * 64;
  const int wN   = (w & 1) * 64;
  const int bid  = blockIdx.x;
  const int id   = (bid & 7) * 64 + (bid >> 3);    // XCD-bijective remap
  const int bn   = id & 7;
  const int bm   = id >> 3;
  const int srow  = tid >> 2;
  const int spart = tid & 3;

  facc acc[4][4] = {};
  const u16* Ag = A + (size_t)(bm * 128 + srow) * 2048 + spart * 8;
  const u16* Bg = Bt + (size_t)(bn * 128 + srow) * 1024 + spart * 8;
  char* ldsA = (char*)As + tid * 16;
  char* ldsB = (char*)Bs + tid * 16;

  for (int k0 = 0; k0 < 1024; k0 += 32) {
    __syncthreads();
    gload16(Ag + k0, ldsA);
    gload16(Ag + (size_t)64 * 2048 + k0, ldsA + 4096);
    gload16(Bg + k0, ldsB);
    gload16(Bg + (size_t)64 * 1024 + k0, ldsB + 4096);
    __syncthreads();

    bfrag af[4], bf[4];
#pragma unroll
    for (int i = 0; i < 4; ++i)
      af[i] = *(const bfrag*)(&As[(wM + i * 16 + l16) * 32 + quad * 8]);
#pragma unroll
    for (int j = 0; j < 4; ++j)
      bf[j] = *(const bfrag*)(&Bs[(wN + j * 16 + l16) * 32 + quad * 8]);
#pragma unroll
    for (int i = 0; i < 4; ++i)
#pragma unroll
      for (int j = 0; j < 4; ++j)
        acc[i][j] = __builtin_amdgcn_mfma_f32_16x16x32_bf16(af[i], bf[j], acc[i][j], 0, 0, 0);
  }

#pragma unroll
  for (int i = 0; i < 4; ++i) {
    const int grow0 = bm * 128 + wM + i * 16 + quad * 4;
#pragma unroll
    for (int j = 0; j < 4; ++j) {
      const int gcol = bn * 128 + wN + j * 16 + l16;
      const float bv = biasf[gcol];
#pragma unroll
      for (int r = 0; r < 4; ++r) {
        const float v = acc[i][j][r] + bv;
        if (isb) ((u16*)Cout)[(size_t)(grow0 + r) * 1024 + gcol] = f2bf(v);
        else     ((float*)Cout)[(size_t)(grow0 + r) * 1024 + gcol] = v;
      }
    }
  }
}

// ---------------------------------------------------------------- flash attention
// R5/R8 structure (proven): 2 waves × 64 q each, gload_lds dbuf K/V with
// both-sides XOR swizzle, in-register P via MFMA k-order freedom, MFMA den.
__global__ __launch_bounds__(128, 2) void attn_kernel(u16* __restrict__ qk,
                                                      const u16* __restrict__ vtg,
                                                      const float* __restrict__ cbias) {
  const int id    = blockIdx.x;             // 0..1023
  const int chunk = id >> 3;
  const int qt    = chunk & 15;
  const int hg    = (id & 7) | ((chunk >> 4) << 3);
  const int h     = hg & 15;
  const int b     = hg >> 4;

  __shared__ u16 KV[2][2][64 * 64];  // [buf][K|V][row*64+col], linear, src-swizzled

  const int tid  = threadIdx.x;      // 0..127
  const int w    = tid >> 6;         // 0..1
  const int lane = tid & 63;
  const int quad = lane >> 4;
  const int l16  = lane & 15;

  // Q: wave w owns q rows qt*128 + w*64 + qs*16 + l16, qs = 0..3
  bfrag bq[4][2];
#pragma unroll
  for (int qs = 0; qs < 4; ++qs) {
    const u16* qrow = qk + (size_t)(b * NSEQ + qt * 128 + w * 64 + qs * 16 + l16) * 2048 + h * HDIM;
    bq[qs][0] = *(const bfrag*)(qrow + quad * 8);
    bq[qs][1] = *(const bfrag*)(qrow + 32 + quad * 8);
  }

  // ones A-fragment for the denominator MFMA (k-order invariant)
  bfrag ones;
#pragma unroll
  for (int i = 0; i < 8; ++i) ones[i] = (short)0x3F80;   // bf16 1.0

  facc den[4] = {};
  facc o[4][4] = {};

  const u16* kbase = qk + (size_t)(b * NSEQ) * 2048 + DMODEL + h * HDIM;
  const u16* vbase = vtg + (size_t)((b * NHEAD + h) * HDIM) * NSEQ;

  // staging chunk map: chunk c = tid + i*128 → row c>>3, swizzled 16B-slot (c&7)^(row&7)
  int crow[4], csc[4];
#pragma unroll
  for (int i = 0; i < 4; ++i) {
    const int c = tid + i * 128;
    crow[i] = c >> 3;
    csc[i]  = (c & 7) ^ (crow[i] & 7);
  }

  // read-side swizzle constants (elem offsets)
  const int e    = l16 & 7;
  const int swk0 = (quad ^ e) * 8;                 // K half-0 chunk
  const int cA0  = ((quad >> 1) ^ e) * 8 + (quad & 1) * 4;  // V base

  auto stage = [&](int sel, int t) {
#pragma unroll
    for (int i = 0; i < 4; ++i) {
      const int c = tid + i * 128;
      gload16(kbase + (size_t)(t * 64 + crow[i]) * 2048 + csc[i] * 8, &KV[sel][0][c * 8]);
      gload16(vbase + (size_t)crow[i] * 2048 + t * 64 + csc[i] * 8,   &KV[sel][1][c * 8]);
    }
  };

  stage(0, 0);

  for (int t = 0; t < NSEQ / 64; ++t) {
    __syncthreads();                 // drains own gloads (implicit vmcnt(0)) + barrier
    if (t + 1 < NSEQ / 64) stage((t + 1) & 1, t + 1);   // writes the OTHER buffer

    const u16* Kb = KV[t & 1][0];
    const u16* Vb = KV[t & 1][1];

    // K fragments (swizzled b128)
    bfrag ak[4][2];
#pragma unroll
    for (int nt = 0; nt < 4; ++nt) {
      const u16* kr = &Kb[(nt * 16 + l16) * 64];
      ak[nt][0] = *(const bfrag*)(kr + swk0);
      ak[nt][1] = *(const bfrag*)(kr + (swk0 ^ 32));
    }

    // V fragments in the bp-matching k-order (swizzled b64 pairs):
    // av[dt][half] elem j = V^T[dt*16+l16][ half*32 + (j>>2)*16 + quad*4 + (j&3) ]
    bfrag av[4][2];
#pragma unroll
    for (int dt = 0; dt < 4; ++dt) {
      const u16* vr = &Vb[(dt * 16 + l16) * 64];
      union { bfrag f; uint2 u2[2]; } un0, un1;
      un0.u2[0] = *(const uint2*)(vr + cA0);
      un0.u2[1] = *(const uint2*)(vr + (cA0 ^ 16));
      un1.u2[0] = *(const uint2*)(vr + (cA0 ^ 32));
      un1.u2[1] = *(const uint2*)(vr + (cA0 ^ 48));
      av[dt][0] = un0.f;
      av[dt][1] = un1.f;
    }

    // per-tile column bias as MFMA C-init (kv-only, shared by all qs)
    facc zb[4];
    if (t < 8) {
      const float* cb = cbias + b * NCTXC + t * 64 + quad * 4;
#pragma unroll
      for (int nt = 0; nt < 4; ++nt) zb[nt] = *(const facc*)(cb + nt * 16);
    } else {
#pragma unroll
      for (int nt = 0; nt < 4; ++nt) zb[nt] = (facc){};
    }

    // 4 q-subtiles: QK -> exp2 -> in-register pack -> PV + den
#pragma unroll
    for (int qs = 0; qs < 4; ++qs) {
      facc s[4];
      __builtin_amdgcn_s_setprio(1);
#pragma unroll
      for (int nt = 0; nt < 4; ++nt) {
        facc z = zb[nt];
        z = __builtin_amdgcn_mfma_f32_16x16x32_bf16(ak[nt][0], bq[qs][0], z, 0, 0, 0);
        s[nt] = __builtin_amdgcn_mfma_f32_16x16x32_bf16(ak[nt][1], bq[qs][1], z, 0, 0, 0);
      }
      __builtin_amdgcn_s_setprio(0);

#pragma unroll
      for (int nt = 0; nt < 4; ++nt)
#pragma unroll
        for (int r = 0; r < 4; ++r)
          s[nt][r] = __builtin_amdgcn_exp2f(s[nt][r]);

      // bp[half] slot j holds P[kv = half*32 + (j>>2)*16 + quad*4 + (j&3)][l16]
      union { bfrag f; uint32_t wrd[4]; } bp0, bp1;
      bp0.wrd[0] = pk2bf(s[0][0], s[0][1]);
      bp0.wrd[1] = pk2bf(s[0][2], s[0][3]);
      bp0.wrd[2] = pk2bf(s[1][0], s[1][1]);
      bp0.wrd[3] = pk2bf(s[1][2], s[1][3]);
      bp1.wrd[0] = pk2bf(s[2][0], s[2][1]);
      bp1.wrd[1] = pk2bf(s[2][2], s[2][3]);
      bp1.wrd[2] = pk2bf(s[3][0], s[3][1]);
      bp1.wrd[3] = pk2bf(s[3][2], s[3][3]);

      __builtin_amdgcn_s_setprio(1);
#pragma unroll
      for (int dt = 0; dt < 4; ++dt) {
        o[qs][dt] = __builtin_amdgcn_mfma_f32_16x16x32_bf16(av[dt][0], bp0.f, o[qs][dt], 0, 0, 0);
        o[qs][dt] = __builtin_amdgcn_mfma_f32_16x16x32_bf16(av[dt][1], bp1.f, o[qs][dt], 0, 0, 0);
      }
      den[qs] = __builtin_amdgcn_mfma_f32_16x16x32_bf16(ones, bp0.f, den[qs], 0, 0, 0);
      den[qs] = __builtin_amdgcn_mfma_f32_16x16x32_bf16(ones, bp1.f, den[qs], 0, 0, 0);
      __builtin_amdgcn_s_setprio(0);
    }
  }

  // epilogue: every lane holds its q-column's denominator at den[qs][0]
#pragma unroll
  for (int qs = 0; qs < 4; ++qs) {
    const float inv = 1.0f / den[qs][0];
    u16* orow = qk + (size_t)(b * NSEQ + qt * 128 + w * 64 + qs * 16 + l16) * 2048 + h * HDIM;
#pragma unroll
    for (int dt = 0; dt < 4; ++dt) {
      uint2 st;
      st.x = pk2bf(o[qs][dt][0] * inv, o[qs][dt][1] * inv);
      st.y = pk2bf(o[qs][dt][2] * inv, o[qs][dt][3] * inv);
      *(uint2*)(orow + dt * 16 + quad * 4) = st;
    }
  }
}

// ---------------------------------------------------------------- launch

extern "C" void kernel_launch(void* const* d_in, const int* in_sizes, int n_in,
                              void* d_out, int out_size, void* d_ws, size_t ws_size,
                              hipStream_t stream) {
  const void* x          = d_in[0];
  const void* ctx_ppr    = d_in[1];
  const void* ctx_trust  = d_in[2];
  const void* W_in       = d_in[3];
  const void* b_in       = d_in[4];
  const void* W_out      = d_in[5];
  const void* b_out      = d_in[6];
  const void* lppr_alpha = d_in[7];
  const void* tscale     = d_in[8];

  char* ws = (char*)d_ws;
  u16* Wt    = (u16*)ws;  ws += (size_t)3072 * 1024 * 2;    //  6 MB  W_in^T bf16
  u16* WoT   = (u16*)ws;  ws += (size_t)1024 * 1024 * 2;    //  2 MB  W_out^T bf16
  u16* qk    = (u16*)ws;  ws += (size_t)8192 * 2048 * 2;    // 32 MB  [Q|K]; attn-out overwrites Q-plane
  u16* Vtg   = (u16*)ws;  ws += (size_t)64 * 64 * 2048 * 2; // 16 MB  gated V^T [b*16+h][d][n]
  u16* xb    = (u16*)ws;  ws += (size_t)8192 * 1024 * 2;    // 16 MB  x as bf16
  float* bin_f  = (float*)ws; ws += 3072 * 4;
  float* bout_f = (float*)ws; ws += 1024 * 4;
  float* gate   = (float*)ws; ws += (size_t)BATCH * NCTXC * 4;
  float* cbias  = (float*)ws; ws += (size_t)BATCH * NCTXC * 4;
  int*   flag   = (int*)ws;   ws += 64;

  detect_kernel<<<dim3(1), dim3(256), 0, stream>>>((const u16*)x, flag);
  // fused prep: cast_x + both transposes + small preps — 4 launches -> 1,
  // no duplicated detect (blocks read flag[0], same as cast_x always did).
  prep_fused<<<dim3(4096 + 3072 + 1024 + 24), dim3(256), 0, stream>>>(
      x, xb, W_in, W_out, Wt, WoT, b_in, b_out, ctx_ppr, ctx_trust,
      lppr_alpha, tscale, bin_f, bout_f, gate, cbias, flag);
  // merged QK GEMM (1024 blocks) + V^T GEMM (512 blocks), XCD-swizzled
  gemm_qkvt<<<dim3(1536), dim3(256), 0, stream>>>(xb, Wt, bin_f, gate, qk, Vtg);
  // fused biased attention (128-q, XCD-swizzled, 2 waves × 64 q, gload_lds dbuf)
  attn_kernel<<<dim3(1024), dim3(128), 0, stream>>>(qk, Vtg, cbias);
  // output GEMM: [8192x1024 (lda 2048)] @ [1024x1024] (+b_out) -> d_out, XCD-swizzled
  gemm_out<<<dim3(512), dim3(256), 0, stream>>>(qk, WoT, bout_f, d_out, flag);
}